// Round 4
// baseline (393.138 us; speedup 1.0000x reference)
//
#include <hip/hip_runtime.h>
#include <hip/hip_bf16.h>

// BPNN: B=512, N=2048, F=64, T=4, H1=64, H2=32.
// out[b] = sum_n MLP_{t[n]}(x[b,n,:]), MLP = silu(W0 x+b0) -> silu(W1 h+b1) -> w2.h+b2
//
// R7: occupancy/granularity package.
//  - R6 evidence: the 1-GiB workspace poison fill is UNCONDITIONAL (persisted
//    with zero d_ws usage) -> using d_ws is free. Global type-sort restored.
//  - 1-wave blocks: 64 threads, NCHUNK=16, grid (128,32)=4096 blocks. No
//    __syncthreads, no LDS reduction stage, finer CU fill + tail. ~97% of
//    blocks see a single type (global sort) -> ~1.03 fragment loads/wave.
//  - Atom ids preloaded into lane registers, fetched via readlane (uniform) --
//    removes per-atom index load from the x-address dependent chain.
//  - sort_atoms prepass also zeroes out[] (drops the hipMemsetAsync launch).
//  - R5 despill kept: individually named fragment registers, preheader loads.
//  - 2-deep x staging kept (register shift A<=B).
// MFMA orientation: D = W * x^T (A-frag == B-frag lane mapping, verified R2).

#define B_ 512
#define N_ 2048
#define F_ 64
#define T_ 4
#define H1_ 64
#define H2_ 32

#define BT 16          // b-tile (MFMA N dim)
#define NCHUNK 16      // sorted atoms per (1-wave) block

typedef __attribute__((ext_vector_type(8))) short bf16x8;
typedef __attribute__((ext_vector_type(4))) short bf16x4;
typedef __attribute__((ext_vector_type(4))) float f32x4;

__device__ inline float silu_f(float v) {
    return v * __builtin_amdgcn_rcpf(1.0f + __expf(-v));
}

__device__ inline bf16x8 pack8(float4 a, float4 b) {
    union { __hip_bfloat162 h[4]; bf16x8 v; } u;
    u.h[0] = __float22bfloat162_rn({a.x, a.y});
    u.h[1] = __float22bfloat162_rn({a.z, a.w});
    u.h[2] = __float22bfloat162_rn({b.x, b.y});
    u.h[3] = __float22bfloat162_rn({b.z, b.w});
    return u.v;
}

__device__ inline bf16x4 pack4(float a, float b, float c, float d) {
    union { __hip_bfloat162 h[2]; bf16x4 v; } u;
    u.h[0] = __float22bfloat162_rn({a, b});
    u.h[1] = __float22bfloat162_rn({c, d});
    return u.v;
}

__device__ inline float bf_at(bf16x4 v, int r) {
    union { bf16x4 v; __hip_bfloat16 h[4]; } u; u.v = v;
    return __bfloat162float(u.h[r]);
}

// ---- prepass: one wave; zero out[]; ordered counting sort of an[] -> (t<<16)|n ----
__global__ void sort_atoms(const int* __restrict__ an, int* __restrict__ sorted,
                           float* __restrict__ out) {
    const int lane = threadIdx.x;
#pragma unroll
    for (int i = 0; i < B_ / 64; ++i) out[i * 64 + lane] = 0.0f;

    int v[32];
#pragma unroll
    for (int c = 0; c < 32; ++c) v[c] = an[c * 64 + lane];

    int c0 = 0, c1 = 0, c2 = 0;
#pragma unroll
    for (int c = 0; c < 32; ++c) {
        c0 += __popcll(__ballot(v[c] == 0));
        c1 += __popcll(__ballot(v[c] == 1));
        c2 += __popcll(__ballot(v[c] == 2));
    }
    int base0 = 0, base1 = c0, base2 = c0 + c1, base3 = c0 + c1 + c2;
    const unsigned long long mb = (1ull << lane) - 1ull;
#pragma unroll
    for (int c = 0; c < 32; ++c) {
        const int t = v[c];
        unsigned long long m0 = __ballot(t == 0);
        unsigned long long m1 = __ballot(t == 1);
        unsigned long long m2 = __ballot(t == 2);
        unsigned long long m3 = __ballot(t == 3);
        int pos;
        if (t == 0)      pos = base0 + (int)__popcll(m0 & mb);
        else if (t == 1) pos = base1 + (int)__popcll(m1 & mb);
        else if (t == 2) pos = base2 + (int)__popcll(m2 & mb);
        else             pos = base3 + (int)__popcll(m3 & mb);
        sorted[pos] = (t << 16) | (c * 64 + lane);
        base0 += (int)__popcll(m0); base1 += (int)__popcll(m1);
        base2 += (int)__popcll(m2); base3 += (int)__popcll(m3);
    }
}

__global__ __launch_bounds__(64, 3) void bpnn_kernel(
    const float* __restrict__ x, const int* __restrict__ sorted,
    const float* __restrict__ w0, const float* __restrict__ b0,
    const float* __restrict__ w1, const float* __restrict__ b1,
    const float* __restrict__ w2, const float* __restrict__ b2,
    float* __restrict__ out)
{
    __shared__ __align__(16) __hip_bfloat16 trb[BT][68]; // 2176 B transpose buf [b][h]

    const int lane = threadIdx.x;
    const int lr   = lane & 15;      // b-col (B,C) / row (A)
    const int q    = lane >> 4;      // quad
    const int b0i  = blockIdx.y * BT;
    const int s0   = blockIdx.x * NCHUNK;

    // preload this block's 16 sorted ids into lanes 0..15 (readlane later)
    int myid = 0;
    if (lane < NCHUNK) myid = sorted[s0 + lane];

    const float* xb_ = x + (size_t)(b0i + lr) * (N_ * F_) + q * 8;
    __hip_bfloat16* trbw = &trb[lr][0];

    float esum0 = 0.f, esum1 = 0.f, bsum = 0.f;

    // fragment registers: individually named -> guaranteed registers
    bf16x8 aw000, aw001, aw010, aw011, aw020, aw021, aw030, aw031;
    bf16x8 aw100, aw101, aw110, aw111;
    bf16x4 b0f0, b0f1, b0f2, b0f3, b1f0, b1f1, w2f0, w2f1;
    float b2c = 0.f;

    // 2-deep x staging
    int i = 0;
    int id0 = __builtin_amdgcn_readlane(myid, 0);
    int id1 = __builtin_amdgcn_readlane(myid, 1);
    float4 sa0, sa1, sa2, sa3, sb0, sb1, sb2, sb3;
    {
        const float4* pA = reinterpret_cast<const float4*>(xb_ + (size_t)(id0 & 0xFFFF) * F_);
        sa0 = pA[0]; sa1 = pA[1]; sa2 = pA[8]; sa3 = pA[9];
        const float4* pB = reinterpret_cast<const float4*>(xb_ + (size_t)(id1 & 0xFFFF) * F_);
        sb0 = pB[0]; sb1 = pB[1]; sb2 = pB[8]; sb3 = pB[9];
    }

    while (i < NCHUNK) {
        const int t = id0 >> 16;
        // ---- load fragments for type t (unconditional, top of run) ----
        {
            const float* wb = w0 + t * (H1_ * F_) + lr * F_ + q * 8;
            const float4* pw;
            pw = reinterpret_cast<const float4*>(wb +  0 * F_ +  0); aw000 = pack8(pw[0], pw[1]);
            pw = reinterpret_cast<const float4*>(wb +  0 * F_ + 32); aw001 = pack8(pw[0], pw[1]);
            pw = reinterpret_cast<const float4*>(wb + 16 * F_ +  0); aw010 = pack8(pw[0], pw[1]);
            pw = reinterpret_cast<const float4*>(wb + 16 * F_ + 32); aw011 = pack8(pw[0], pw[1]);
            pw = reinterpret_cast<const float4*>(wb + 32 * F_ +  0); aw020 = pack8(pw[0], pw[1]);
            pw = reinterpret_cast<const float4*>(wb + 32 * F_ + 32); aw021 = pack8(pw[0], pw[1]);
            pw = reinterpret_cast<const float4*>(wb + 48 * F_ +  0); aw030 = pack8(pw[0], pw[1]);
            pw = reinterpret_cast<const float4*>(wb + 48 * F_ + 32); aw031 = pack8(pw[0], pw[1]);
            const float* wc = w1 + t * (H2_ * H1_) + lr * H1_ + q * 8;
            pw = reinterpret_cast<const float4*>(wc +  0 * H1_ +  0); aw100 = pack8(pw[0], pw[1]);
            pw = reinterpret_cast<const float4*>(wc +  0 * H1_ + 32); aw101 = pack8(pw[0], pw[1]);
            pw = reinterpret_cast<const float4*>(wc + 16 * H1_ +  0); aw110 = pack8(pw[0], pw[1]);
            pw = reinterpret_cast<const float4*>(wc + 16 * H1_ + 32); aw111 = pack8(pw[0], pw[1]);
            float4 v;
            v = *reinterpret_cast<const float4*>(b0 + t * H1_ +  0 + q * 4); b0f0 = pack4(v.x, v.y, v.z, v.w);
            v = *reinterpret_cast<const float4*>(b0 + t * H1_ + 16 + q * 4); b0f1 = pack4(v.x, v.y, v.z, v.w);
            v = *reinterpret_cast<const float4*>(b0 + t * H1_ + 32 + q * 4); b0f2 = pack4(v.x, v.y, v.z, v.w);
            v = *reinterpret_cast<const float4*>(b0 + t * H1_ + 48 + q * 4); b0f3 = pack4(v.x, v.y, v.z, v.w);
            v = *reinterpret_cast<const float4*>(b1 + t * H2_ +  0 + q * 4); b1f0 = pack4(v.x, v.y, v.z, v.w);
            v = *reinterpret_cast<const float4*>(b1 + t * H2_ + 16 + q * 4); b1f1 = pack4(v.x, v.y, v.z, v.w);
            v = *reinterpret_cast<const float4*>(w2 + t * H2_ +  0 + q * 4); w2f0 = pack4(v.x, v.y, v.z, v.w);
            v = *reinterpret_cast<const float4*>(w2 + t * H2_ + 16 + q * 4); w2f1 = pack4(v.x, v.y, v.z, v.w);
            b2c = b2[t];
        }

        // ---- inner loop over this type run (fragments read-only) ----
        for (;;) {
            bf16x8 xf0 = pack8(sa0, sa1);            // data prefetched >=2 atoms ago
            bf16x8 xf1 = pack8(sa2, sa3);
            sa0 = sb0; sa1 = sb1; sa2 = sb2; sa3 = sb3;   // shift pipeline A <= B
            int in2 = (i + 2 < NCHUNK) ? i + 2 : NCHUNK - 1;
            int idn = __builtin_amdgcn_readlane(myid, in2);
            {
                const float4* pB = reinterpret_cast<const float4*>(xb_ + (size_t)(idn & 0xFFFF) * F_);
                sb0 = pB[0]; sb1 = pB[1]; sb2 = pB[8]; sb3 = pB[9];
            }
            bsum += b2c;

            // ---- layer 0: D0[64h x 16b] = W0_t * x^T ----
            f32x4 acc0 = {0.f,0.f,0.f,0.f}, acc1 = {0.f,0.f,0.f,0.f};
            f32x4 acc2 = {0.f,0.f,0.f,0.f}, acc3 = {0.f,0.f,0.f,0.f};
            acc0 = __builtin_amdgcn_mfma_f32_16x16x32_bf16(aw000, xf0, acc0, 0, 0, 0);
            acc0 = __builtin_amdgcn_mfma_f32_16x16x32_bf16(aw001, xf1, acc0, 0, 0, 0);
            acc1 = __builtin_amdgcn_mfma_f32_16x16x32_bf16(aw010, xf0, acc1, 0, 0, 0);
            acc1 = __builtin_amdgcn_mfma_f32_16x16x32_bf16(aw011, xf1, acc1, 0, 0, 0);
            acc2 = __builtin_amdgcn_mfma_f32_16x16x32_bf16(aw020, xf0, acc2, 0, 0, 0);
            acc2 = __builtin_amdgcn_mfma_f32_16x16x32_bf16(aw021, xf1, acc2, 0, 0, 0);
            acc3 = __builtin_amdgcn_mfma_f32_16x16x32_bf16(aw030, xf0, acc3, 0, 0, 0);
            acc3 = __builtin_amdgcn_mfma_f32_16x16x32_bf16(aw031, xf1, acc3, 0, 0, 0);

            // bias + silu; lane holds h = nt*16 + q*4 + r, b = lr
            {
                float v0 = silu_f(acc0[0] + bf_at(b0f0, 0));
                float v1 = silu_f(acc0[1] + bf_at(b0f0, 1));
                float v2 = silu_f(acc0[2] + bf_at(b0f0, 2));
                float v3 = silu_f(acc0[3] + bf_at(b0f0, 3));
                *reinterpret_cast<bf16x4*>(trbw +  0 + q * 4) = pack4(v0, v1, v2, v3);
                v0 = silu_f(acc1[0] + bf_at(b0f1, 0));
                v1 = silu_f(acc1[1] + bf_at(b0f1, 1));
                v2 = silu_f(acc1[2] + bf_at(b0f1, 2));
                v3 = silu_f(acc1[3] + bf_at(b0f1, 3));
                *reinterpret_cast<bf16x4*>(trbw + 16 + q * 4) = pack4(v0, v1, v2, v3);
                v0 = silu_f(acc2[0] + bf_at(b0f2, 0));
                v1 = silu_f(acc2[1] + bf_at(b0f2, 1));
                v2 = silu_f(acc2[2] + bf_at(b0f2, 2));
                v3 = silu_f(acc2[3] + bf_at(b0f2, 3));
                *reinterpret_cast<bf16x4*>(trbw + 32 + q * 4) = pack4(v0, v1, v2, v3);
                v0 = silu_f(acc3[0] + bf_at(b0f3, 0));
                v1 = silu_f(acc3[1] + bf_at(b0f3, 1));
                v2 = silu_f(acc3[2] + bf_at(b0f3, 2));
                v3 = silu_f(acc3[3] + bf_at(b0f3, 3));
                *reinterpret_cast<bf16x4*>(trbw + 48 + q * 4) = pack4(v0, v1, v2, v3);
            }
            __builtin_amdgcn_wave_barrier();  // order LDS write->read (per-wave buffer)

            bf16x8 hb0 = *reinterpret_cast<const bf16x8*>(trbw + q * 8);
            bf16x8 hb1 = *reinterpret_cast<const bf16x8*>(trbw + 32 + q * 8);
            __builtin_amdgcn_wave_barrier();

            // ---- layer 1: D1[32g x 16b] = W1_t * h1 ----
            f32x4 acB0 = {0.f,0.f,0.f,0.f}, acB1 = {0.f,0.f,0.f,0.f};
            acB0 = __builtin_amdgcn_mfma_f32_16x16x32_bf16(aw100, hb0, acB0, 0, 0, 0);
            acB0 = __builtin_amdgcn_mfma_f32_16x16x32_bf16(aw101, hb1, acB0, 0, 0, 0);
            acB1 = __builtin_amdgcn_mfma_f32_16x16x32_bf16(aw110, hb0, acB1, 0, 0, 0);
            acB1 = __builtin_amdgcn_mfma_f32_16x16x32_bf16(aw111, hb1, acB1, 0, 0, 0);

            // ---- layer 2: lane accumulates w2[g]*silu(.) over its 8 g ----
#pragma unroll
            for (int r = 0; r < 4; ++r) {
                esum0 += silu_f(acB0[r] + bf_at(b1f0, r)) * bf_at(w2f0, r);
                esum1 += silu_f(acB1[r] + bf_at(b1f1, r)) * bf_at(w2f1, r);
            }

            ++i;
            id0 = id1; id1 = idn;
            if (i >= NCHUNK || (id0 >> 16) != t) break;
        }
    }

    // reduce esum over the 4 quads holding the same b (lane bits 4-5)
    float esum = esum0 + esum1;
    esum += __shfl_xor(esum, 16);
    esum += __shfl_xor(esum, 32);
    if (q == 0) atomicAdd(&out[b0i + lr], esum + bsum);  // bsum wave-uniform: add once
}

extern "C" void kernel_launch(void* const* d_in, const int* in_sizes, int n_in,
                              void* d_out, int out_size, void* d_ws, size_t ws_size,
                              hipStream_t stream) {
    const float* x  = (const float*)d_in[0];
    const int*   an = (const int*)d_in[1];
    const float* w0 = (const float*)d_in[2];
    const float* b0 = (const float*)d_in[3];
    const float* w1 = (const float*)d_in[4];
    const float* b1 = (const float*)d_in[5];
    const float* w2 = (const float*)d_in[6];
    const float* b2 = (const float*)d_in[7];
    float* out = (float*)d_out;
    int* sorted = (int*)d_ws;            // 2048 ints = 8 KB (ws poison fill is unconditional)

    sort_atoms<<<1, 64, 0, stream>>>(an, sorted, out);    // also zeroes out[]
    dim3 grid(N_ / NCHUNK, B_ / BT);                      // (128, 32) = 4096 blocks
    bpnn_kernel<<<grid, 64, 0, stream>>>(x, sorted, w0, b0, w1, b1, w2, b2, out);
}

// Round 5
// 384.267 us; speedup vs baseline: 1.0231x; 1.0231x over previous
//
#include <hip/hip_runtime.h>
#include <hip/hip_bf16.h>

// BPNN: B=512, N=2048, F=64, T=4, H1=64, H2=32.
// out[b] = sum_n MLP_{t[n]}(x[b,n,:]), MLP = silu(W0 x+b0) -> silu(W1 h+b1) -> w2.h+b2
//
// R8: fire-and-forget global_load_lds staging of x (T3/T4 pattern).
//  Evidence: kernel pinned at ~121us (~35% BW) across R6 (4-wave) and R7
//  (1-wave) register-prefetch variants -> stall is the x load path itself:
//  each VMEM instr touches 16 scattered 128B lines and the register consume
//  drains the wave's loads every iteration. Fix: decouple via DMA-to-LDS:
//  - per-wave private 3-slot x ring in LDS (3 x 4KB); wave stages atom i+3
//    with 4x global_load_lds(width=16) -- no landing VGPRs, no full drain;
//  - counted s_waitcnt vmcnt(8) before consuming atom i (never 0 in loop);
//  - read-back 4x ds_read_b128, then pack to bf16 (index map verified:
//    stage instr c holds row bytes c*64+qs*16 at LDS c*1024+qs*256+lr*16;
//    lane(lr,q) frag = {q*32, +16, 128+q*32, +16} -> offsets
//    (q>>1)*1024+(q&1)*512+lr*16 + {0,256,2048,2304}).
//  Compute path (frags/MFMA/silu/trb) identical to R7. Global type-sort via
//  d_ws kept (ws poison fill is unconditional -> free). 4-wave blocks,
//  NCHUNK=64, LDS 57.9KB -> 2 blocks/CU.
// MFMA orientation: D = W * x^T (A-frag == B-frag lane mapping, verified R2).

#define B_ 512
#define N_ 2048
#define F_ 64
#define T_ 4
#define H1_ 64
#define H2_ 32

#define BT 16          // b-tile (MFMA N dim)
#define WAVES 4
#define NCHUNK 64      // sorted atoms per block (16 per wave)
#define WSLICE 16      // atoms per wave
#define NSLOT 3        // LDS ring depth (atoms in flight per wave)

typedef __attribute__((ext_vector_type(8))) short bf16x8;
typedef __attribute__((ext_vector_type(4))) short bf16x4;
typedef __attribute__((ext_vector_type(4))) float f32x4;

typedef const __attribute__((address_space(1))) void* gas_ptr;
typedef __attribute__((address_space(3))) void* las_ptr;

__device__ inline float silu_f(float v) {
    return v * __builtin_amdgcn_rcpf(1.0f + __expf(-v));
}

__device__ inline bf16x8 pack8(float4 a, float4 b) {
    union { __hip_bfloat162 h[4]; bf16x8 v; } u;
    u.h[0] = __float22bfloat162_rn({a.x, a.y});
    u.h[1] = __float22bfloat162_rn({a.z, a.w});
    u.h[2] = __float22bfloat162_rn({b.x, b.y});
    u.h[3] = __float22bfloat162_rn({b.z, b.w});
    return u.v;
}

__device__ inline bf16x4 pack4(float a, float b, float c, float d) {
    union { __hip_bfloat162 h[2]; bf16x4 v; } u;
    u.h[0] = __float22bfloat162_rn({a, b});
    u.h[1] = __float22bfloat162_rn({c, d});
    return u.v;
}

__device__ inline float bf_at(bf16x4 v, int r) {
    union { bf16x4 v; __hip_bfloat16 h[4]; } u; u.v = v;
    return __bfloat162float(u.h[r]);
}

// ---- prepass: one wave; zero out[]; ordered counting sort of an[] -> (t<<16)|n ----
__global__ void sort_atoms(const int* __restrict__ an, int* __restrict__ sorted,
                           float* __restrict__ out) {
    const int lane = threadIdx.x;
#pragma unroll
    for (int i = 0; i < B_ / 64; ++i) out[i * 64 + lane] = 0.0f;

    int v[32];
#pragma unroll
    for (int c = 0; c < 32; ++c) v[c] = an[c * 64 + lane];

    int c0 = 0, c1 = 0, c2 = 0;
#pragma unroll
    for (int c = 0; c < 32; ++c) {
        c0 += __popcll(__ballot(v[c] == 0));
        c1 += __popcll(__ballot(v[c] == 1));
        c2 += __popcll(__ballot(v[c] == 2));
    }
    int base0 = 0, base1 = c0, base2 = c0 + c1, base3 = c0 + c1 + c2;
    const unsigned long long mb = (1ull << lane) - 1ull;
#pragma unroll
    for (int c = 0; c < 32; ++c) {
        const int t = v[c];
        unsigned long long m0 = __ballot(t == 0);
        unsigned long long m1 = __ballot(t == 1);
        unsigned long long m2 = __ballot(t == 2);
        unsigned long long m3 = __ballot(t == 3);
        int pos;
        if (t == 0)      pos = base0 + (int)__popcll(m0 & mb);
        else if (t == 1) pos = base1 + (int)__popcll(m1 & mb);
        else if (t == 2) pos = base2 + (int)__popcll(m2 & mb);
        else             pos = base3 + (int)__popcll(m3 & mb);
        sorted[pos] = (t << 16) | (c * 64 + lane);
        base0 += (int)__popcll(m0); base1 += (int)__popcll(m1);
        base2 += (int)__popcll(m2); base3 += (int)__popcll(m3);
    }
}

__global__ __launch_bounds__(256) void bpnn_kernel(
    const float* __restrict__ x, const int* __restrict__ sorted,
    const float* __restrict__ w0, const float* __restrict__ b0,
    const float* __restrict__ w1, const float* __restrict__ b1,
    const float* __restrict__ w2, const float* __restrict__ b2,
    float* __restrict__ out)
{
    __shared__ __align__(16) char xlds[WAVES][NSLOT][4096];     // 48 KB x ring
    __shared__ __align__(16) __hip_bfloat16 trb[WAVES][BT][68]; // 8704 B transpose buf

    const int tid  = threadIdx.x;
    const int wave = tid >> 6;
    const int lane = tid & 63;
    const int lr   = lane & 15;      // b-col (B,C) / row (A)
    const int q    = lane >> 4;      // quad
    const int b0i  = blockIdx.y * BT;

    // all 64 lanes hold this block's 64 sorted ids (same in every wave)
    const int myid = sorted[blockIdx.x * NCHUNK + lane];
    const int w16  = wave * WSLICE;

    // per-lane global row base for staging: row (b0i+lr), lane-chunk qs = q
    const char* growbase = (const char*)x
        + ((size_t)(b0i + lr) * (N_ * F_)) * sizeof(float) + (size_t)q * 16;
    char* xw = &xlds[wave][0][0];
    __hip_bfloat16* trbw = &trb[wave][lr][0];

    // stage atom n into ring slot s: 4 x global_load_lds width=16
    auto stage = [&](int s, int n) {
        const char* g = growbase + (size_t)n * 256;
        char* l = xw + s * 4096;
#pragma unroll
        for (int c = 0; c < 4; ++c) {
            __builtin_amdgcn_global_load_lds((gas_ptr)(g + c * 64),
                                             (las_ptr)(l + c * 1024), 16, 0, 0);
        }
    };

    // prologue: fill the ring (atoms 0,1,2 of this wave's slice)
    stage(0, __builtin_amdgcn_readlane(myid, w16 + 0) & 0xFFFF);
    stage(1, __builtin_amdgcn_readlane(myid, w16 + 1) & 0xFFFF);
    stage(2, __builtin_amdgcn_readlane(myid, w16 + 2) & 0xFFFF);

    float esum0 = 0.f, esum1 = 0.f, bsum = 0.f;

    // fragment registers: individually named -> guaranteed registers
    bf16x8 aw000, aw001, aw010, aw011, aw020, aw021, aw030, aw031;
    bf16x8 aw100, aw101, aw110, aw111;
    bf16x4 b0f0, b0f1, b0f2, b0f3, b1f0, b1f1, w2f0, w2f1;
    float b2c = 0.f;
    int cur_t = -1;
    int slot = 0;

    const char* rbase = xw + ((q >> 1) << 10) + ((q & 1) << 9) + (lr << 4);

    for (int i = 0; i < WSLICE; ++i) {
        const int id = __builtin_amdgcn_readlane(myid, w16 + i);
        const int t  = id >> 16;
        if (t != cur_t) {            // rare (globally sorted): frag reload
            cur_t = t;
            const float* wb = w0 + t * (H1_ * F_) + lr * F_ + q * 8;
            const float4* pw;
            pw = reinterpret_cast<const float4*>(wb +  0 * F_ +  0); aw000 = pack8(pw[0], pw[1]);
            pw = reinterpret_cast<const float4*>(wb +  0 * F_ + 32); aw001 = pack8(pw[0], pw[1]);
            pw = reinterpret_cast<const float4*>(wb + 16 * F_ +  0); aw010 = pack8(pw[0], pw[1]);
            pw = reinterpret_cast<const float4*>(wb + 16 * F_ + 32); aw011 = pack8(pw[0], pw[1]);
            pw = reinterpret_cast<const float4*>(wb + 32 * F_ +  0); aw020 = pack8(pw[0], pw[1]);
            pw = reinterpret_cast<const float4*>(wb + 32 * F_ + 32); aw021 = pack8(pw[0], pw[1]);
            pw = reinterpret_cast<const float4*>(wb + 48 * F_ +  0); aw030 = pack8(pw[0], pw[1]);
            pw = reinterpret_cast<const float4*>(wb + 48 * F_ + 32); aw031 = pack8(pw[0], pw[1]);
            const float* wc = w1 + t * (H2_ * H1_) + lr * H1_ + q * 8;
            pw = reinterpret_cast<const float4*>(wc +  0 * H1_ +  0); aw100 = pack8(pw[0], pw[1]);
            pw = reinterpret_cast<const float4*>(wc +  0 * H1_ + 32); aw101 = pack8(pw[0], pw[1]);
            pw = reinterpret_cast<const float4*>(wc + 16 * H1_ +  0); aw110 = pack8(pw[0], pw[1]);
            pw = reinterpret_cast<const float4*>(wc + 16 * H1_ + 32); aw111 = pack8(pw[0], pw[1]);
            float4 v;
            v = *reinterpret_cast<const float4*>(b0 + t * H1_ +  0 + q * 4); b0f0 = pack4(v.x, v.y, v.z, v.w);
            v = *reinterpret_cast<const float4*>(b0 + t * H1_ + 16 + q * 4); b0f1 = pack4(v.x, v.y, v.z, v.w);
            v = *reinterpret_cast<const float4*>(b0 + t * H1_ + 32 + q * 4); b0f2 = pack4(v.x, v.y, v.z, v.w);
            v = *reinterpret_cast<const float4*>(b0 + t * H1_ + 48 + q * 4); b0f3 = pack4(v.x, v.y, v.z, v.w);
            v = *reinterpret_cast<const float4*>(b1 + t * H2_ +  0 + q * 4); b1f0 = pack4(v.x, v.y, v.z, v.w);
            v = *reinterpret_cast<const float4*>(b1 + t * H2_ + 16 + q * 4); b1f1 = pack4(v.x, v.y, v.z, v.w);
            v = *reinterpret_cast<const float4*>(w2 + t * H2_ +  0 + q * 4); w2f0 = pack4(v.x, v.y, v.z, v.w);
            v = *reinterpret_cast<const float4*>(w2 + t * H2_ + 16 + q * 4); w2f1 = pack4(v.x, v.y, v.z, v.w);
            b2c = b2[t];
        }

        // ---- counted wait: atom i's 4 staged loads are the oldest ----
        if (i < WSLICE - 2)      asm volatile("s_waitcnt vmcnt(8)" ::: "memory");
        else if (i == WSLICE - 2) asm volatile("s_waitcnt vmcnt(4)" ::: "memory");
        else                      asm volatile("s_waitcnt vmcnt(0)" ::: "memory");

        // ---- LDS read-back of atom i (slot) ----
        const char* rb = rbase + slot * 4096;
        float4 f0 = *reinterpret_cast<const float4*>(rb);
        float4 f1 = *reinterpret_cast<const float4*>(rb + 256);
        float4 f2 = *reinterpret_cast<const float4*>(rb + 2048);
        float4 f3 = *reinterpret_cast<const float4*>(rb + 2304);
        asm volatile("s_waitcnt lgkmcnt(0)" ::: "memory");  // reads done before DMA reuse
        __builtin_amdgcn_sched_barrier(0);

        // ---- refill freed slot with atom i+3 (fire-and-forget) ----
        if (i + NSLOT < WSLICE) {
            int idn = __builtin_amdgcn_readlane(myid, w16 + i + NSLOT);
            stage(slot, idn & 0xFFFF);
        }
        slot = (slot == NSLOT - 1) ? 0 : slot + 1;

        bf16x8 xf0 = pack8(f0, f1);
        bf16x8 xf1 = pack8(f2, f3);
        bsum += b2c;

        // ---- layer 0: D0[64h x 16b] = W0_t * x^T ----
        f32x4 acc0 = {0.f,0.f,0.f,0.f}, acc1 = {0.f,0.f,0.f,0.f};
        f32x4 acc2 = {0.f,0.f,0.f,0.f}, acc3 = {0.f,0.f,0.f,0.f};
        acc0 = __builtin_amdgcn_mfma_f32_16x16x32_bf16(aw000, xf0, acc0, 0, 0, 0);
        acc0 = __builtin_amdgcn_mfma_f32_16x16x32_bf16(aw001, xf1, acc0, 0, 0, 0);
        acc1 = __builtin_amdgcn_mfma_f32_16x16x32_bf16(aw010, xf0, acc1, 0, 0, 0);
        acc1 = __builtin_amdgcn_mfma_f32_16x16x32_bf16(aw011, xf1, acc1, 0, 0, 0);
        acc2 = __builtin_amdgcn_mfma_f32_16x16x32_bf16(aw020, xf0, acc2, 0, 0, 0);
        acc2 = __builtin_amdgcn_mfma_f32_16x16x32_bf16(aw021, xf1, acc2, 0, 0, 0);
        acc3 = __builtin_amdgcn_mfma_f32_16x16x32_bf16(aw030, xf0, acc3, 0, 0, 0);
        acc3 = __builtin_amdgcn_mfma_f32_16x16x32_bf16(aw031, xf1, acc3, 0, 0, 0);

        // bias + silu; lane holds h = nt*16 + q*4 + r, b = lr
        {
            float v0 = silu_f(acc0[0] + bf_at(b0f0, 0));
            float v1 = silu_f(acc0[1] + bf_at(b0f0, 1));
            float v2 = silu_f(acc0[2] + bf_at(b0f0, 2));
            float v3 = silu_f(acc0[3] + bf_at(b0f0, 3));
            *reinterpret_cast<bf16x4*>(trbw +  0 + q * 4) = pack4(v0, v1, v2, v3);
            v0 = silu_f(acc1[0] + bf_at(b0f1, 0));
            v1 = silu_f(acc1[1] + bf_at(b0f1, 1));
            v2 = silu_f(acc1[2] + bf_at(b0f1, 2));
            v3 = silu_f(acc1[3] + bf_at(b0f1, 3));
            *reinterpret_cast<bf16x4*>(trbw + 16 + q * 4) = pack4(v0, v1, v2, v3);
            v0 = silu_f(acc2[0] + bf_at(b0f2, 0));
            v1 = silu_f(acc2[1] + bf_at(b0f2, 1));
            v2 = silu_f(acc2[2] + bf_at(b0f2, 2));
            v3 = silu_f(acc2[3] + bf_at(b0f2, 3));
            *reinterpret_cast<bf16x4*>(trbw + 32 + q * 4) = pack4(v0, v1, v2, v3);
            v0 = silu_f(acc3[0] + bf_at(b0f3, 0));
            v1 = silu_f(acc3[1] + bf_at(b0f3, 1));
            v2 = silu_f(acc3[2] + bf_at(b0f3, 2));
            v3 = silu_f(acc3[3] + bf_at(b0f3, 3));
            *reinterpret_cast<bf16x4*>(trbw + 48 + q * 4) = pack4(v0, v1, v2, v3);
        }
        __builtin_amdgcn_wave_barrier();  // order LDS write->read (per-wave buffer)

        bf16x8 hb0 = *reinterpret_cast<const bf16x8*>(trbw + q * 8);
        bf16x8 hb1 = *reinterpret_cast<const bf16x8*>(trbw + 32 + q * 8);
        __builtin_amdgcn_wave_barrier();

        // ---- layer 1: D1[32g x 16b] = W1_t * h1 ----
        f32x4 acB0 = {0.f,0.f,0.f,0.f}, acB1 = {0.f,0.f,0.f,0.f};
        acB0 = __builtin_amdgcn_mfma_f32_16x16x32_bf16(aw100, hb0, acB0, 0, 0, 0);
        acB0 = __builtin_amdgcn_mfma_f32_16x16x32_bf16(aw101, hb1, acB0, 0, 0, 0);
        acB1 = __builtin_amdgcn_mfma_f32_16x16x32_bf16(aw110, hb0, acB1, 0, 0, 0);
        acB1 = __builtin_amdgcn_mfma_f32_16x16x32_bf16(aw111, hb1, acB1, 0, 0, 0);

        // ---- layer 2: lane accumulates w2[g]*silu(.) over its 8 g ----
#pragma unroll
        for (int r = 0; r < 4; ++r) {
            esum0 += silu_f(acB0[r] + bf_at(b1f0, r)) * bf_at(w2f0, r);
            esum1 += silu_f(acB1[r] + bf_at(b1f1, r)) * bf_at(w2f1, r);
        }
    }

    // reduce esum over the 4 quads holding the same b (lane bits 4-5)
    float esum = esum0 + esum1;
    esum += __shfl_xor(esum, 16);
    esum += __shfl_xor(esum, 32);
    if (q == 0) atomicAdd(&out[b0i + lr], esum + bsum);  // bsum wave-uniform: add once
}

extern "C" void kernel_launch(void* const* d_in, const int* in_sizes, int n_in,
                              void* d_out, int out_size, void* d_ws, size_t ws_size,
                              hipStream_t stream) {
    const float* x  = (const float*)d_in[0];
    const int*   an = (const int*)d_in[1];
    const float* w0 = (const float*)d_in[2];
    const float* b0 = (const float*)d_in[3];
    const float* w1 = (const float*)d_in[4];
    const float* b1 = (const float*)d_in[5];
    const float* w2 = (const float*)d_in[6];
    const float* b2 = (const float*)d_in[7];
    float* out = (float*)d_out;
    int* sorted = (int*)d_ws;            // 8 KB of d_ws (poison fill is unconditional)

    sort_atoms<<<1, 64, 0, stream>>>(an, sorted, out);    // also zeroes out[]
    dim3 grid(N_ / NCHUNK, B_ / BT);                      // (32, 32) = 1024 blocks
    bpnn_kernel<<<grid, 256, 0, stream>>>(x, sorted, w0, b0, w1, b1, w2, b2, out);
}